// Round 8
// baseline (294.601 us; speedup 1.0000x reference)
//
#include <hip/hip_runtime.h>
#include <hip/hip_cooperative_groups.h>

namespace cg = cooperative_groups;

#define B_ 16
#define N_ 1024
#define C_ 768
#define E_ 8
#define H_ 192

typedef __bf16 bf16x8 __attribute__((ext_vector_type(8)));
typedef __bf16 bf16x4 __attribute__((ext_vector_type(4)));
typedef float  f32x4  __attribute__((ext_vector_type(4)));

// ---------------------------------------------------------------------------
// Kernel 1: prep. (a) pack fc1_w/fc2_w to bf16 in MFMA-B-fragment order:
//   pw1[e][kb=c/32][n=h][c%32], pw2[e][kb=h/32][n=c][h%32]
// (b) transpose gate_w to gwT[d][j][c] (f32); rows 0..7 clean, 8..15 noise.
// ---------------------------------------------------------------------------
__global__ __launch_bounds__(256) void prep_kernel(
    const float* __restrict__ w1, const float* __restrict__ w2,
    const float* __restrict__ gw,
    __bf16* __restrict__ pw1, __bf16* __restrict__ pw2,
    float* __restrict__ gwT) {
  int idx = blockIdx.x * 256 + threadIdx.x;            // float4 index
  const int nW4 = (E_ * H_ * C_) / 4;                  // 294912
  if (idx >= nW4) return;
  int flat = idx * 4;
  int e = flat / (H_ * C_);
  int r = flat - e * (H_ * C_);

  // w1: [e][h][c] -> pw1
  {
    float4 a = *(const float4*)(w1 + (size_t)flat);
    int n = r / C_;           // h
    int c = r - n * C_;       // c, %4==0
    size_t o = ((size_t)(e * 24 + (c >> 5)) * 192 + n) * 32 + (c & 31);
    pw1[o + 0] = (__bf16)a.x; pw1[o + 1] = (__bf16)a.y;
    pw1[o + 2] = (__bf16)a.z; pw1[o + 3] = (__bf16)a.w;
  }
  // w2: [e][c][h] -> pw2
  {
    float4 a = *(const float4*)(w2 + (size_t)flat);
    int n = r / H_;           // c index 0..767
    int h = r - n * H_;       // 0..191, %4==0
    size_t o = ((size_t)(e * 6 + (h >> 5)) * 768 + n) * 32 + (h & 31);
    pw2[o + 0] = (__bf16)a.x; pw2[o + 1] = (__bf16)a.y;
    pw2[o + 2] = (__bf16)a.z; pw2[o + 3] = (__bf16)a.w;
  }
  // gwT: [d][c][16] -> [d][j][c]
  if (idx < (4 * 16 * C_) / 4) {
    int f = idx * 4;
    int d = f / (16 * C_);
    int rr = f - d * (16 * C_);
    int j = rr / C_;
    int c = rr - j * C_;      // %4==0
    const float* src = gw + (size_t)d * C_ * 16 + j;
    float4 v;
    v.x = src[(size_t)(c + 0) * 16]; v.y = src[(size_t)(c + 1) * 16];
    v.z = src[(size_t)(c + 2) * 16]; v.w = src[(size_t)(c + 3) * 16];
    *(float4*)(gwT + (size_t)f) = v;
  }
}

// ---------------------------------------------------------------------------
// Kernel 2 (cooperative): gate + top-2 + 2-expert adapter fused.
// Grid = 256 blocks x 768 thr (12 waves, 1 block/CU). x is read ONCE:
// Phase 1: 4 groups of 16 tokens; stage f32->LDS (exact gating dots) and
//   convert same-thread to the bf16 MFMA tile. Dot mapping is the R0-proven
//   broadcast pattern (16 lanes share one gwT row; 3 column-chunks of 256)
//   -- fixing R2's 32-address/wave mistake. Per-block partials -> psums.
// grid.sync(); per-sample reduce + top-2.
// Phase 2: R7 expert body verbatim (3 waves/SIMD, M=32/wave, depth-3/2
//   register pipelines, XCD-pinned). Eliminates gate_kernel's 50 MB x
//   re-read (~13 us) and one dispatch.
// ---------------------------------------------------------------------------
#define XS_OFF   0                         // bf16 xs[64][776]   = 99328
#define XF_OFF   99328                     // f32  xf[16][772]   = 49408 (ph1)
#define HS_OFF   99328                     // bf16 hs[64][200]   = 25600 (ph2)
#define SC_OFF   (99328 + 49408)           // f32 sc[16][16][3]  = 3072
#define RED_OFF  (SC_OFF + 3072)           // f32 red[16][8]     = 512
#define BS_OFF   (RED_OFF + 512)           // f32 bsum[8]+smc[8] = 64
#define SMEM_FUSED (BS_OFF + 64)           // 152384 B

__global__ __launch_bounds__(768, 3) void fused_kernel(
    const float* __restrict__ x, const int* __restrict__ task_ids,
    const float* __restrict__ eps, const float* __restrict__ gwT,
    const __bf16* __restrict__ pw1, const __bf16* __restrict__ pw2,
    const float* __restrict__ fc1_b, const float* __restrict__ fc2_b,
    float* __restrict__ psums, float* __restrict__ out) {
  const int bid = blockIdx.x;
  const int sxc = bid >> 3;                    // 0..31 within an XCD
  const int b = (bid & 7) * 2 + (sxc >> 4);    // 2 consecutive samples / XCD
  const int token0 = (sxc & 15) * 64;
  const int tid = threadIdx.x;
  const int wave = tid >> 6;
  const int wm = wave / 6;                     // token half (0/1)
  const int wn = wave - wm * 6;                // N slice (0..5)
  const int lane = tid & 63;
  const int ln = lane & 15;
  const int q8 = (lane >> 4) * 8;
  const int q4 = (lane >> 4) * 4;
  const int arow = wm * 32;
  const int task = task_ids[b];

  extern __shared__ char smem[];
  __bf16 (*xs)[776] = reinterpret_cast<__bf16(*)[776]>(smem + XS_OFF);
  float  (*xf)[772] = reinterpret_cast<float(*)[772]>(smem + XF_OFF);
  __bf16 (*hs)[200] = reinterpret_cast<__bf16(*)[200]>(smem + HS_OFF);
  float (*sc)[16][3] = reinterpret_cast<float(*)[16][3]>(smem + SC_OFF);
  float (*red)[8] = reinterpret_cast<float(*)[8]>(smem + RED_OFF);
  float* bsum = reinterpret_cast<float*>(smem + BS_OFF);
  float* smc  = bsum + 8;

  if (tid < 8) bsum[tid] = 0.0f;

  // ---- Phase 1: 4 groups of 16 tokens -------------------------------------
  const float* xbase = x + ((size_t)b * N_ + token0) * C_;
  for (int g = 0; g < 4; ++g) {
    // stage 16x768 f32 -> xf, and convert same-thread -> xs (bf16 tile)
    for (int it = 0; it < 4; ++it) {
      int chunk = it * 768 + tid;              // 0..3071
      int row = chunk / 192;
      int col4 = (chunk - row * 192) * 4;
      float4 v = *(const float4*)(xbase + ((size_t)(g * 16 + row)) * C_ + col4);
      *(float4*)&xf[row][col4] = v;
      bf16x4 o;
      o[0] = (__bf16)v.x; o[1] = (__bf16)v.y; o[2] = (__bf16)v.z; o[3] = (__bf16)v.w;
      *(bf16x4*)&xs[g * 16 + row][col4] = o;
    }
    __syncthreads();

    // gating dots: thread = (chunk ck 0..2, t, j); 16 lanes share one gwT
    // row (broadcast); each thread dots 256 elems in f32 (exact).
    {
      const int ck = tid >> 8;                 // 0..2
      const int vt = tid & 255;
      const int t = vt & 15;
      const int j = vt >> 4;
      const float* wr = gwT + ((size_t)task * 16 + j) * C_ + ck * 256;
      const float* xr_ = &xf[t][ck * 256];
      float acc = 0.0f;
#pragma unroll 4
      for (int c = 0; c < 256; c += 4) {
        f32x4 xv = *(const f32x4*)(xr_ + c);
        f32x4 wv = *(const f32x4*)(wr + c);
        acc += xv[0] * wv[0] + xv[1] * wv[1] + xv[2] * wv[2] + xv[3] * wv[3];
      }
      sc[t][j][ck] = acc;
    }
    __syncthreads();

    // per-token logit: clean + eps * (softplus(raw) + 0.01)
    if (tid < 128) {
      int t = tid >> 3, e2 = tid & 7;
      float clean = sc[t][e2][0] + sc[t][e2][1] + sc[t][e2][2];
      float raw   = sc[t][e2 + 8][0] + sc[t][e2 + 8][1] + sc[t][e2 + 8][2];
      float sp = (raw > 20.0f) ? raw : log1pf(expf(raw));
      red[t][e2] = clean +
          eps[((size_t)b * N_ + token0 + g * 16 + t) * E_ + e2] * (sp + 0.01f);
    }
    __syncthreads();
    if (tid < 8) {
      float s = bsum[tid];
#pragma unroll
      for (int t = 0; t < 16; ++t) s += red[t][tid];
      bsum[tid] = s;
    }
    __syncthreads();
  }
  if (tid < 8) psums[bid * 8 + tid] = bsum[tid];
  __threadfence();

  cg::this_grid().sync();

  // per-sample reduce over the sample's 16 tile-blocks
  if (tid < 8) {
    float s = 0.0f;
#pragma unroll
    for (int tile = 0; tile < 16; ++tile) {
      int srcbid = (((b & 1) * 16 + tile) << 3) | (b >> 1);
      s += psums[srcbid * 8 + tid];
    }
    smc[tid] = s;
  }
  __syncthreads();

  // top-2 (tie rule matches lax.top_k: strict >, stable)
  int e_idx[2]; float gate_v[2];
  {
    float best = -INFINITY, best2 = -INFINITY;
    int i1 = 0, i2 = 0;
#pragma unroll
    for (int e = 0; e < E_; ++e) {
      float v = smc[e];
      if (v > best) { best2 = best; i2 = i1; best = v; i1 = e; }
      else if (v > best2) { best2 = v; i2 = e; }
    }
    float d = best - best2;
    float st = d / (d + 1e-6f);
    float et = expf(st);
    e_idx[0] = i1; gate_v[0] = et / (et + 1.0f);
    e_idx[1] = i2; gate_v[1] = 1.0f / (et + 1.0f);
  }

  // ---- Phase 2: expert compute (R7 body) ----------------------------------
  bf16x8 bq[3][2];
  {
    const __bf16* w1l = pw1 + (size_t)e_idx[0] * (24 * 192 * 32)
                            + (size_t)(wn * 32 + ln) * 32 + q8;
#pragma unroll
    for (int k0 = 0; k0 < 3; ++k0)
#pragma unroll
      for (int jj = 0; jj < 2; ++jj)
        bq[k0][jj] = *(const bf16x8*)(w1l + (size_t)k0 * 6144 + jj * 512);
  }

  f32x4 c2[2][8] = {};   // persistent y accumulator (gate folded into h)

  for (int kx = 0; kx < 2; ++kx) {
    const int e = e_idx[kx];
    const float g = gate_v[kx];

    // GEMM1: h = x @ W1^T. M=32 (2 frags), N-slice 32 (wn), K=768 (24 kb).
    const __bf16* w1l = pw1 + (size_t)e * (24 * 192 * 32)
                            + (size_t)(wn * 32 + ln) * 32 + q8;
    if (kx == 1) {
#pragma unroll
      for (int k0 = 0; k0 < 3; ++k0)
#pragma unroll
        for (int jj = 0; jj < 2; ++jj)
          bq[k0][jj] = *(const bf16x8*)(w1l + (size_t)k0 * 6144 + jj * 512);
    }
    bf16x8 aq[3][2];
#pragma unroll
    for (int k0 = 0; k0 < 3; ++k0) {
      aq[k0][0] = *(const bf16x8*)&xs[arow + ln][k0 * 32 + q8];
      aq[k0][1] = *(const bf16x8*)&xs[arow + 16 + ln][k0 * 32 + q8];
    }
    f32x4 c1[2][2] = {};
#pragma unroll
    for (int kb = 0; kb < 24; ++kb) {
      const int p = kb % 3;
#pragma unroll
      for (int jj = 0; jj < 2; ++jj) {
        c1[0][jj] = __builtin_amdgcn_mfma_f32_16x16x32_bf16(aq[p][0], bq[p][jj], c1[0][jj], 0, 0, 0);
        c1[1][jj] = __builtin_amdgcn_mfma_f32_16x16x32_bf16(aq[p][1], bq[p][jj], c1[1][jj], 0, 0, 0);
      }
      if (kb < 21) {
        const int kn = kb + 3;
        const __bf16* nx = w1l + (size_t)kn * 6144;
#pragma unroll
        for (int jj = 0; jj < 2; ++jj) bq[p][jj] = *(const bf16x8*)(nx + jj * 512);
        aq[p][0] = *(const bf16x8*)&xs[arow + ln][kn * 32 + q8];
        aq[p][1] = *(const bf16x8*)&xs[arow + 16 + ln][kn * 32 + q8];
      }
    }
    // bias + exact gelu + gate scale -> hs (bf16)
#pragma unroll
    for (int jj = 0; jj < 2; ++jj) {
      int col = wn * 32 + jj * 16 + ln;
      float b1 = fc1_b[e * H_ + col];
#pragma unroll
      for (int m = 0; m < 2; ++m) {
#pragma unroll
        for (int r = 0; r < 4; ++r) {
          int row = arow + m * 16 + q4 + r;
          float v = c1[m][jj][r] + b1;
          float gl = 0.5f * v * (1.0f + erff(v * 0.70710678118f));
          hs[row][col] = (__bf16)(g * gl);
        }
      }
    }
    __syncthreads();

    // GEMM2: y += h @ W2^T. M=32, N-slice 128 (wn) in TWO 64-col passes.
#pragma unroll
    for (int pass = 0; pass < 2; ++pass) {
      const __bf16* w2l = pw2 + (size_t)e * (6 * 768 * 32)
                              + (size_t)(wn * 128 + pass * 64 + ln) * 32 + q8;
      bf16x8 bh[2][4], av[2][2];
#pragma unroll
      for (int jj = 0; jj < 4; ++jj) bh[0][jj] = *(const bf16x8*)(w2l + jj * 512);
      av[0][0] = *(const bf16x8*)&hs[arow + ln][q8];
      av[0][1] = *(const bf16x8*)&hs[arow + 16 + ln][q8];
#pragma unroll
      for (int kb = 0; kb < 6; ++kb) {
        const int p = kb & 1;
        if (kb < 5) {
          const __bf16* src = w2l + (size_t)(kb + 1) * 24576;
#pragma unroll
          for (int jj = 0; jj < 4; ++jj)
            bh[p ^ 1][jj] = *(const bf16x8*)(src + jj * 512);
          av[p ^ 1][0] = *(const bf16x8*)&hs[arow + ln][(kb + 1) * 32 + q8];
          av[p ^ 1][1] = *(const bf16x8*)&hs[arow + 16 + ln][(kb + 1) * 32 + q8];
        }
#pragma unroll
        for (int jj = 0; jj < 4; ++jj) {
          const int cj = pass * 4 + jj;
          c2[0][cj] = __builtin_amdgcn_mfma_f32_16x16x32_bf16(av[p][0], bh[p][jj], c2[0][cj], 0, 0, 0);
          c2[1][cj] = __builtin_amdgcn_mfma_f32_16x16x32_bf16(av[p][1], bh[p][jj], c2[1][cj], 0, 0, 0);
        }
      }
    }
    __syncthreads();   // protect hs before next expert overwrites
  }

  // epilogue: out = x + y (+ gate-weighted fc2_b)
  const float* xr = x + ((size_t)b * N_ + token0) * C_;
  float* outr = out + ((size_t)b * N_ + token0) * C_;
#pragma unroll
  for (int jj = 0; jj < 8; ++jj) {
    int col = wn * 128 + jj * 16 + ln;
    float b2t = gate_v[0] * fc2_b[e_idx[0] * C_ + col] +
                gate_v[1] * fc2_b[e_idx[1] * C_ + col];
#pragma unroll
    for (int m = 0; m < 2; ++m) {
#pragma unroll
      for (int r = 0; r < 4; ++r) {
        int row = arow + m * 16 + q4 + r;
        size_t off = (size_t)row * C_ + col;
        outr[off] = xr[off] + c2[m][jj][r] + b2t;
      }
    }
  }
}

// ---------------------------------------------------------------------------
extern "C" void kernel_launch(void* const* d_in, const int* in_sizes, int n_in,
                              void* d_out, int out_size, void* d_ws, size_t ws_size,
                              hipStream_t stream) {
  const float* x      = (const float*)d_in[0];
  const int*   task   = (const int*)d_in[1];
  const float* eps    = (const float*)d_in[2];
  const float* gate_w = (const float*)d_in[3];
  const float* fc1_w  = (const float*)d_in[4];
  const float* fc1_b  = (const float*)d_in[5];
  const float* fc2_w  = (const float*)d_in[6];
  const float* fc2_b  = (const float*)d_in[7];
  float* out = (float*)d_out;

  // workspace: pw1 | pw2 | gwT | psums  (~4.92 MB)
  const size_t nW = (size_t)E_ * H_ * C_;              // 1179648
  __bf16* pw1 = (__bf16*)d_ws;
  __bf16* pw2 = pw1 + nW;
  float* gwT   = (float*)((char*)d_ws + 2 * nW * sizeof(__bf16));
  float* psums = gwT + 4 * 16 * C_;                    // 256*8 floats

  prep_kernel<<<(nW / 4 + 255) / 256, 256, 0, stream>>>(fc1_w, fc2_w, gate_w,
                                                        pw1, pw2, gwT);

  hipFuncSetAttribute(reinterpret_cast<const void*>(fused_kernel),
                      hipFuncAttributeMaxDynamicSharedMemorySize, SMEM_FUSED);
  void* args[] = {(void*)&x, (void*)&task, (void*)&eps, (void*)&gwT,
                  (void*)&pw1, (void*)&pw2, (void*)&fc1_b, (void*)&fc2_b,
                  (void*)&psums, (void*)&out};
  hipLaunchCooperativeKernel(reinterpret_cast<void*>(fused_kernel),
                             dim3(B_ * 16), dim3(768), args, SMEM_FUSED,
                             stream);
}